// Round 2
// 338.982 us; speedup vs baseline: 1.0537x; 1.0537x over previous
//
#include <hip/hip_runtime.h>
#include <hip/hip_fp16.h>
#include <math.h>
#include <limits.h>

#define N_NODES 50000
#define N_EDGES 800000
#define NEG 0.2f

typedef _Float16 half8 __attribute__((ext_vector_type(8)));
typedef float floatx4 __attribute__((ext_vector_type(4)));

// ---------------- CSR build ----------------

__global__ void zero_kernel(int* a, int n) {
    int i = blockIdx.x * blockDim.x + threadIdx.x;
    if (i < n) a[i] = 0;
}

// 4 edges/thread: one int4 load, 4 independent fire-and-forget atomics
__global__ void count_kernel(const int* __restrict__ dst, int* cnt, int E) {
    int t = blockIdx.x * blockDim.x + threadIdx.x;
    int i0 = t * 4;
    if (i0 + 3 < E) {
        int4 d4 = *(const int4*)(dst + i0);
        atomicAdd(&cnt[d4.x], 1);
        atomicAdd(&cnt[d4.y], 1);
        atomicAdd(&cnt[d4.z], 1);
        atomicAdd(&cnt[d4.w], 1);
    } else {
        for (int i = i0; i < E; ++i) atomicAdd(&cnt[dst[i]], 1);
    }
}

__global__ void scan1_kernel(const int* __restrict__ cnt, int* rowptr, int* partials, int n) {
    __shared__ int sh[256];
    int tid = threadIdx.x;
    int i = blockIdx.x * 256 + tid;
    int v = (i < n) ? cnt[i] : 0;
    sh[tid] = v;
    __syncthreads();
    for (int off = 1; off < 256; off <<= 1) {
        int t = (tid >= off) ? sh[tid - off] : 0;
        __syncthreads();
        sh[tid] += t;
        __syncthreads();
    }
    if (i < n) rowptr[i] = sh[tid] - v;
    if (tid == 255) partials[blockIdx.x] = sh[255];
}

__global__ void scan2_kernel(int* partials, int nb) {
    __shared__ int sh[256];
    int tid = threadIdx.x;
    int v = (tid < nb) ? partials[tid] : 0;
    sh[tid] = v;
    __syncthreads();
    for (int off = 1; off < 256; off <<= 1) {
        int t = (tid >= off) ? sh[tid - off] : 0;
        __syncthreads();
        sh[tid] += t;
        __syncthreads();
    }
    if (tid < nb) partials[tid] = sh[tid] - v;
}

// also emits cursor = rowptr (free) so fill_kernel can atomicAdd directly
__global__ void scan3_kernel(int* rowptr, const int* __restrict__ partials, int* cursor, int n) {
    int i = blockIdx.x * blockDim.x + threadIdx.x;
    if (i < n) {
        int v = rowptr[i] + partials[i >> 8];
        rowptr[i] = v;
        cursor[i] = v;
    }
    if (i == 0) rowptr[n] = N_EDGES;
}

// scatter fill: 4 edges/thread, ONE 4B scattered store per edge.
// Stores the EDGE ID into col; sortrow sorts ids (== original edge order,
// bitwise-deterministic) and then maps id -> src in place. This reproduces
// the exact neighbor ordering of the verified round-0 kernel (edge-id order),
// which the numerics depend on (value-order regressed absmax 9.8e-4 -> 1e-2).
__global__ void fill_kernel(const int* __restrict__ dst, int* cursor, int* col, int E) {
    int t = blockIdx.x * blockDim.x + threadIdx.x;
    int i0 = t * 4;
    if (i0 + 3 < E) {
        int4 d4 = *(const int4*)(dst + i0);
        int p0 = atomicAdd(&cursor[d4.x], 1);
        int p1 = atomicAdd(&cursor[d4.y], 1);
        int p2 = atomicAdd(&cursor[d4.z], 1);
        int p3 = atomicAdd(&cursor[d4.w], 1);
        col[p0] = i0;
        col[p1] = i0 + 1;
        col[p2] = i0 + 2;
        col[p3] = i0 + 3;
    } else {
        for (int i = i0; i < E; ++i) {
            int p = atomicAdd(&cursor[dst[i]], 1);
            col[p] = i;
        }
    }
}

// canonicalize: one wave per node, bitonic sort segment of edge ids, then
// map col[p] = src[eid]. Result identical to sorting (eid, src) pairs by eid.
__global__ void sortrow_kernel(const int* __restrict__ rowptr, int* col,
                               const int* __restrict__ src, int n) {
    int wid = (int)((blockIdx.x * blockDim.x + threadIdx.x) >> 6);
    int lane = threadIdx.x & 63;
    if (wid >= n) return;
    int r0 = rowptr[wid], r1 = rowptr[wid + 1];
    int deg = r1 - r0;
    if (deg <= 0) return;
    if (deg == 1) {
        if (lane == 0) col[r0] = src[col[r0]];
        return;
    }
    if (deg <= 64) {
        int key = (lane < deg) ? col[r0 + lane] : INT_MAX;
#pragma unroll
        for (int k = 2; k <= 64; k <<= 1) {
#pragma unroll
            for (int j = k >> 1; j > 0; j >>= 1) {
                int pk = __shfl_xor(key, j);
                bool up = ((lane & k) == 0);
                bool lower = ((lane & j) == 0);
                bool take = lower ? ((pk < key) == up) : ((pk > key) == up);
                if (take) key = pk;
            }
        }
        if (lane < deg) col[r0 + lane] = src[key];
    } else if (lane == 0) {
        // unreachable for Poisson(16) degrees; correct fallback anyway
        for (int i = r0 + 1; i < r1; ++i) {
            int kv = col[i];
            int j = i - 1;
            while (j >= r0 && col[j] > kv) {
                col[j + 1] = col[j];
                --j;
            }
            col[j + 1] = kv;
        }
        for (int i = r0; i < r1; ++i) col[i] = src[col[i]];
    }
}

// ---------------- W[K][192] fp32 -> wt16[192][K] fp16 ----------------
template <int K>
__global__ void wtrans_kernel(const float* __restrict__ W, __half* __restrict__ wt) {
    int idx = blockIdx.x * blockDim.x + threadIdx.x;
    if (idx < 192 * K) {
        int n = idx / K, k = idx - n * K;
        wt[idx] = __float2half(W[k * 192 + n]);
    }
}

// ---------------- MFMA GEMM: A[rows][K] fp32 @ W[K][192] -> h16[rows][192]
// + fused alpha epilogue. Block: 256 thr = 4 waves x 16-row strips.
// A converted to fp16 in-register (same _rn rounding as a staging buffer).
template <int K>
__global__ __launch_bounds__(256) void mfma_gemm_kernel(const float* __restrict__ A,
                                                        const __half* __restrict__ wt,
                                                        __half* __restrict__ out,
                                                        const float* __restrict__ att_src,
                                                        const float* __restrict__ att_dst,
                                                        float* __restrict__ as4,
                                                        float* __restrict__ ad4,
                                                        float* __restrict__ wself4, int rows) {
    constexpr int KP = K + 8;
    __shared__ __align__(16) __half lds[192 * KP];  // wt tile; later reused for output staging
    int tid = threadIdx.x;
    int lane = tid & 63;
    int wv = tid >> 6;
    int ln = lane & 15;
    int q = lane >> 4;

    // stage wt -> LDS [n][KP]
    for (int idx = tid; idx < 192 * (K / 8); idx += 256) {
        int n = idx / (K / 8), kk = (idx % (K / 8)) * 8;
        *(float4*)(lds + n * KP + kk) = *(const float4*)(wt + n * K + kk);
    }

    // A fragments: lane ln -> row m0+ln, quad q -> k offset q*8 (fp32 load, cvt)
    int m0 = blockIdx.x * 64 + wv * 16;
    int m = m0 + ln;
    int mc = m < rows ? m : 0;
    half8 afr[K / 32];
#pragma unroll
    for (int kt = 0; kt < K / 32; ++kt) {
        float4 a0 = *(const float4*)(A + (size_t)mc * K + kt * 32 + q * 8);
        float4 a1 = *(const float4*)(A + (size_t)mc * K + kt * 32 + q * 8 + 4);
        half8 f;
        f[0] = (_Float16)a0.x; f[1] = (_Float16)a0.y; f[2] = (_Float16)a0.z; f[3] = (_Float16)a0.w;
        f[4] = (_Float16)a1.x; f[5] = (_Float16)a1.y; f[6] = (_Float16)a1.z; f[7] = (_Float16)a1.w;
        afr[kt] = f;
    }

    __syncthreads();

    floatx4 acc[12];
#pragma unroll
    for (int c = 0; c < 12; ++c) acc[c] = (floatx4){0.f, 0.f, 0.f, 0.f};

#pragma unroll
    for (int kt = 0; kt < K / 32; ++kt) {
#pragma unroll
        for (int c = 0; c < 12; ++c) {
            half8 b = *(const half8*)(lds + (c * 16 + ln) * KP + kt * 32 + q * 8);
            acc[c] = __builtin_amdgcn_mfma_f32_16x16x32_f16(afr[kt], b, acc[c], 0, 0, 0);
        }
    }

    // fused alpha epilogue: lane holds C rows m0+q*4+r, col c*16+ln
    float asv[12], adv[12];
#pragma unroll
    for (int c = 0; c < 12; ++c) {
        asv[c] = att_src[c * 16 + ln];
        adv[c] = att_dst[c * 16 + ln];
    }
#pragma unroll
    for (int r = 0; r < 4; ++r) {
        float s0 = 0, s1 = 0, s2 = 0, d0 = 0, d1 = 0, d2 = 0;
#pragma unroll
        for (int c = 0; c < 4; ++c) { s0 += acc[c][r] * asv[c]; d0 += acc[c][r] * adv[c]; }
#pragma unroll
        for (int c = 4; c < 8; ++c) { s1 += acc[c][r] * asv[c]; d1 += acc[c][r] * adv[c]; }
#pragma unroll
        for (int c = 8; c < 12; ++c) { s2 += acc[c][r] * asv[c]; d2 += acc[c][r] * adv[c]; }
        for (int off = 1; off < 16; off <<= 1) {
            s0 += __shfl_xor(s0, off); s1 += __shfl_xor(s1, off); s2 += __shfl_xor(s2, off);
            d0 += __shfl_xor(d0, off); d1 += __shfl_xor(d1, off); d2 += __shfl_xor(d2, off);
        }
        int row = m0 + q * 4 + r;
        if (ln == 0 && row < rows) {
            as4[row * 4 + 0] = s0; as4[row * 4 + 1] = s1; as4[row * 4 + 2] = s2;
            ad4[row * 4 + 0] = d0; ad4[row * 4 + 1] = d1; ad4[row * 4 + 2] = d2;
            float v0 = s0 + d0; v0 = v0 > 0.f ? v0 : NEG * v0;
            float v1 = s1 + d1; v1 = v1 > 0.f ? v1 : NEG * v1;
            float v2 = s2 + d2; v2 = v2 > 0.f ? v2 : NEG * v2;
            wself4[row * 4 + 0] = __expf(v0);
            wself4[row * 4 + 1] = __expf(v1);
            wself4[row * 4 + 2] = __expf(v2);
        }
    }

    // h16 store via LDS for coalescing
    __syncthreads();
#pragma unroll
    for (int c = 0; c < 12; ++c)
#pragma unroll
        for (int r = 0; r < 4; ++r)
            lds[(wv * 16 + q * 4 + r) * 192 + c * 16 + ln] = __float2half(acc[c][r]);
    __syncthreads();
    int row0 = blockIdx.x * 64;
    for (int idx = tid; idx < 1536; idx += 256) {
        int row = (idx * 8) / 192, off = (idx * 8) % 192;
        if (row0 + row < rows)
            *(float4*)(out + (size_t)(row0 + row) * 192 + off) = *(float4*)(lds + row * 192 + off);
    }
}

// ---------------- aggregation: one wave per node, fp16 gathers, fully-predicated U=8 ----------------
template <bool RELU>
__global__ __launch_bounds__(256) void aggregate_kernel(const __half* __restrict__ h,
                                                        const float* __restrict__ as_,
                                                        const float* __restrict__ ad4,
                                                        const float* __restrict__ wself4,
                                                        const float* __restrict__ bias,
                                                        const int* __restrict__ rowptr,
                                                        const int* __restrict__ col,
                                                        float* __restrict__ out, int n) {
    constexpr int U = 8;
    __shared__ float sh[4][192];
    int wid = (int)((blockIdx.x * blockDim.x + threadIdx.x) >> 6);
    int l = threadIdx.x & 63;
    int wv = threadIdx.x >> 6;
    bool valid = wid < n;
    int d = valid ? wid : 0;
    if (valid && l < 48) {
        int hl = l >> 4;
        int r0 = rowptr[d], r1 = rowptr[d + 1];
        float adh = ad4[d * 4 + hl];
        float w = wself4[d * 4 + hl];
        float2 sraw = *(const float2*)(h + (size_t)d * 192 + l * 4);
        float2 s01 = __half22float2(*(__half2*)&sraw.x);
        float2 s23 = __half22float2(*(__half2*)&sraw.y);
        float ax = w * s01.x, ay = w * s01.y, az = w * s23.x, aw = w * s23.y;
        float den = w;

        for (int j = r0; j < r1; j += U) {
            int s[U];
            bool act[U];
            float av[U];
            float2 g[U];
#pragma unroll
            for (int u = 0; u < U; ++u) {
                int jj = j + u;
                act[u] = jj < r1;
                s[u] = act[u] ? col[jj] : 0;
            }
#pragma unroll
            for (int u = 0; u < U; ++u) {
                float t = as_[s[u] * 4 + hl];
                av[u] = act[u] ? t : -1e30f;
            }
#pragma unroll
            for (int u = 0; u < U; ++u)
                g[u] = *(const float2*)(h + (size_t)s[u] * 192 + l * 4);
#pragma unroll
            for (int u = 0; u < U; ++u) {
                float v = av[u] + adh;
                v = v > 0.f ? v : NEG * v;
                float we = __expf(v);
                float2 g01 = __half22float2(*(__half2*)&g[u].x);
                float2 g23 = __half22float2(*(__half2*)&g[u].y);
                den += we;
                ax += we * g01.x;
                ay += we * g01.y;
                az += we * g23.x;
                aw += we * g23.y;
            }
        }
        float r = 1.f / den;
        float4 o = {ax * r, ay * r, az * r, aw * r};
        *(float4*)&sh[wv][l * 4] = o;
    }
    __syncthreads();
    if (valid) {
        float o = (sh[wv][l] + sh[wv][64 + l] + sh[wv][128 + l]) * (1.f / 3.f) + bias[l];
        if (RELU) o = fmaxf(o, 0.f);
        out[(size_t)d * 64 + l] = o;
    }
}

extern "C" void kernel_launch(void* const* d_in, const int* in_sizes, int n_in,
                              void* d_out, int out_size, void* d_ws, size_t ws_size,
                              hipStream_t stream) {
    const float* x = (const float*)d_in[0];       // [N,128]
    const int* ei = (const int*)d_in[1];          // [2,E]
    const float* W1 = (const float*)d_in[2];      // [128,192]
    const float* att_s1 = (const float*)d_in[3];  // [3,64] flat 192
    const float* att_d1 = (const float*)d_in[4];
    const float* b1 = (const float*)d_in[5];      // [64]
    const float* W2 = (const float*)d_in[6];      // [64,192]
    const float* att_s2 = (const float*)d_in[7];
    const float* att_d2 = (const float*)d_in[8];
    const float* b2 = (const float*)d_in[9];
    const int* src = ei;
    const int* dst = ei + N_EDGES;

    // workspace layout (16B-aligned blocks)
    __half* h16 = (__half*)d_ws;                           // N*192
    __half* wt1 = h16 + (size_t)N_NODES * 192;             // 192*128
    __half* wt2 = wt1 + 192 * 128;                         // 192*64
    float* as4 = (float*)(wt2 + 192 * 64);                 // N*4
    float* ad4 = as4 + N_NODES * 4;                        // N*4
    float* wself4 = ad4 + N_NODES * 4;                     // N*4
    int* cnt = (int*)(wself4 + N_NODES * 4);               // N (counts, then cursor)
    int* rowptr = cnt + N_NODES;                           // N+1
    int* col = rowptr + N_NODES + 1;                       // E
    int* partials = col + N_EDGES;                         // <=256

    float* outf = (float*)d_out;                           // layer-1 output [N,64] too
    const int NB = (N_NODES + 255) / 256;
    const int E4B = (N_EDGES / 4 + 255) / 256;             // 4 edges/thread grids

    // weight transposes (independent of CSR)
    wtrans_kernel<128><<<(192 * 128 + 255) / 256, 256, 0, stream>>>(W1, wt1);
    wtrans_kernel<64><<<(192 * 64 + 255) / 256, 256, 0, stream>>>(W2, wt2);

    // CSR build (shared by both layers), canonicalized to edge-id order
    zero_kernel<<<(N_NODES + 255) / 256, 256, 0, stream>>>(cnt, N_NODES);
    count_kernel<<<E4B, 256, 0, stream>>>(dst, cnt, N_EDGES);
    scan1_kernel<<<NB, 256, 0, stream>>>(cnt, rowptr, partials, N_NODES);
    scan2_kernel<<<1, 256, 0, stream>>>(partials, NB);
    scan3_kernel<<<NB, 256, 0, stream>>>(rowptr, partials, cnt, N_NODES);  // cnt becomes cursor
    fill_kernel<<<E4B, 256, 0, stream>>>(dst, cnt, col, N_EDGES);
    sortrow_kernel<<<(N_NODES + 3) / 4, 256, 0, stream>>>(rowptr, col, src, N_NODES);

    // layer 1
    mfma_gemm_kernel<128><<<(N_NODES + 63) / 64, 256, 0, stream>>>(x, wt1, h16, att_s1, att_d1,
                                                                   as4, ad4, wself4, N_NODES);
    aggregate_kernel<true><<<(N_NODES + 3) / 4, 256, 0, stream>>>(h16, as4, ad4, wself4, b1,
                                                                  rowptr, col, outf, N_NODES);

    // layer 2
    mfma_gemm_kernel<64><<<(N_NODES + 63) / 64, 256, 0, stream>>>(outf, wt2, h16, att_s2, att_d2,
                                                                  as4, ad4, wself4, N_NODES);
    aggregate_kernel<false><<<(N_NODES + 3) / 4, 256, 0, stream>>>(h16, as4, ad4, wself4, b2,
                                                                   rowptr, col, outf, N_NODES);
}